// Round 10
// baseline (230.763 us; speedup 1.0000x reference)
//
#include <hip/hip_runtime.h>

// Problem constants (Emformer layer)
#define T_   1024
#define B_   16
#define D_   512
#define H_   8
#define R_   32
#define S_   16
#define M_   16
#define TQ_  1072          // R + T + S
#define KL_  1072          // M + R + T
#define DH_  64            // D/H
#define NROW 17152         // TQ*B == KL*B
#define K_   512           // inner dim for ALL three GEMMs
#define LQ_  268           // KL/4 (key-quad groups)
#define QSCALE 0.18033688f // 0.125 * log2(e): folded into Q projection

typedef unsigned short u16;
using bf16x8 = __attribute__((ext_vector_type(8))) short;
using bf16x4 = __attribute__((ext_vector_type(4))) short;
using f32x4  = __attribute__((ext_vector_type(4))) float;
using u16x4  = __attribute__((ext_vector_type(4))) unsigned short;

__device__ __forceinline__ u16 f2bf(float f) {
    unsigned int u = __builtin_bit_cast(unsigned int, f);
    unsigned int r = u + 0x7fffu + ((u >> 16) & 1u);
    return (u16)(r >> 16);
}

// pack 2 f32 -> 2 bf16 in one u32 (RTNE), T12 recipe
__device__ __forceinline__ unsigned int cvt_pk_bf16(float a, float b) {
    unsigned int r;
    asm("v_cvt_pk_bf16_f32 %0, %1, %2" : "=v"(r) : "v"(a), "v"(b));
    return r;
}

// 16x16x16 bf16 MFMA (A,B = 4 bf16 each): PV consumes the QK output's
// natural 4-keys-per-lane granularity -- P stays in registers.
__device__ __forceinline__ f32x4 mfma16(bf16x4 a, bf16x4 b, f32x4 c) {
    asm("v_mfma_f32_16x16x16_bf16 %0, %1, %2, %0" : "+v"(c) : "v"(a), "v"(b));
    return c;
}

// async global->LDS, 16B per lane; LDS dest = wave-uniform base + lane*16
__device__ __forceinline__ void gload_lds16(const u16* g, u16* l) {
    __builtin_amdgcn_global_load_lds(
        (const __attribute__((address_space(1))) unsigned int*)g,
        (__attribute__((address_space(3))) unsigned int*)l,
        16, 0, 0);
}

// bijective XCD swizzle (m204)
__device__ __forceinline__ int xcd_swz(int bid, int nwg) {
    const int q = nwg >> 3, r = nwg & 7;
    const int xcd = bid & 7, idx = bid >> 3;
    return (xcd < r ? xcd * (q + 1) : r * (q + 1) + (xcd - r) * q) + idx;
}

// ---------------------------------------------------------------------------
// Stage 1: single gathered buffer xall = [mems | rc | utt | smr] (17408 rows)
// ---------------------------------------------------------------------------
__global__ void k_convert4(const float4* __restrict__ utt, const float4* __restrict__ rc,
                           const float4* __restrict__ smr, const float4* __restrict__ mems,
                           const float4* __restrict__ Wq, const float4* __restrict__ Wkv,
                           const float4* __restrict__ Wo,
                           u16x4* __restrict__ xall,
                           u16x4* __restrict__ wq, u16x4* __restrict__ wkv,
                           u16x4* __restrict__ wo)
{
    const int N4 = 17408 * D_ / 4;
    const int MB = M_ * B_ * D_ / 4;
    const int RB = MB + R_ * B_ * D_ / 4;
    const int UB = RB + T_ * B_ * D_ / 4;
    const int W1 = D_ * D_ / 4, W2 = 2 * D_ * D_ / 4;
    for (int i = blockIdx.x * blockDim.x + threadIdx.x; i < N4;
         i += gridDim.x * blockDim.x) {
        float4 v;
        if (i < MB)      v = mems[i];
        else if (i < RB) v = rc[i - MB];
        else if (i < UB) v = utt[i - RB];
        else             v = smr[i - UB];
        xall[i] = (u16x4){f2bf(v.x), f2bf(v.y), f2bf(v.z), f2bf(v.w)};
        if (i < W1) { v = Wq[i];  wq[i]  = (u16x4){f2bf(v.x), f2bf(v.y), f2bf(v.z), f2bf(v.w)}; }
        if (i < W2) { v = Wkv[i]; wkv[i] = (u16x4){f2bf(v.x), f2bf(v.y), f2bf(v.z), f2bf(v.w)}; }
        if (i < W1) { v = Wo[i];  wo[i]  = (u16x4){f2bf(v.x), f2bf(v.y), f2bf(v.z), f2bf(v.w)}; }
    }
}

// ---------------------------------------------------------------------------
// m97-structure GEMM core: 256 thr / 4 waves, 128x128 tile, BK=64, single
// 32 KB LDS buffer (passed in, shared by both instantiations), 5 blocks/CU.
// ---------------------------------------------------------------------------
template<bool TOR>
__device__ __forceinline__ void core128(const u16* __restrict__ Ab,
                                        const u16* __restrict__ Wb,
                                        u16* As, u16* Bs, f32x4* acc)
{
    const int tid  = threadIdx.x;
    const int w    = tid >> 6, lane = tid & 63;
    const int col  = lane & 15, quad = lane >> 4;
    const int sr   = tid >> 3;                 // 0..31 staging row in round
    const int sc   = (tid & 7) ^ (sr & 7);     // pre-swizzled source chunk
    const u16* gA  = Ab + (size_t)sr * K_ + sc * 8;
    const u16* gB  = Wb + (size_t)sr * K_ + sc * 8;

#pragma unroll
    for (int i = 0; i < 16; i++) acc[i] = (f32x4){0.f, 0.f, 0.f, 0.f};

    for (int kt = 0; kt < 8; ++kt) {
        __syncthreads();
#pragma unroll
        for (int i = 0; i < 4; i++)
            gload_lds16(gA + (size_t)(i * 32) * K_ + kt * 64,
                        &As[(i * 32 + w * 8) * 64]);
#pragma unroll
        for (int i = 0; i < 4; i++)
            gload_lds16(gB + (size_t)(i * 32) * K_ + kt * 64,
                        &Bs[(i * 32 + w * 8) * 64]);
        __syncthreads();
#pragma unroll
        for (int kh = 0; kh < 2; ++kh) {
            bf16x8 aF[2], bF[8];
#pragma unroll
            for (int mi = 0; mi < 2; mi++)
                aF[mi] = *(const bf16x8*)&As[(w * 32 + mi * 16 + col) * 64
                             + (((kh * 4 + quad) ^ (col & 7)) * 8)];
#pragma unroll
            for (int ni = 0; ni < 8; ni++)
                bF[ni] = *(const bf16x8*)&Bs[(ni * 16 + col) * 64
                             + (((kh * 4 + quad) ^ (col & 7)) * 8)];
            if (TOR) {
#pragma unroll
                for (int ni = 0; ni < 8; ni++)
#pragma unroll
                    for (int mi = 0; mi < 2; mi++)
                        acc[ni * 2 + mi] = __builtin_amdgcn_mfma_f32_16x16x32_bf16(
                            bF[ni], aF[mi], acc[ni * 2 + mi], 0, 0, 0);
            } else {
#pragma unroll
                for (int mi = 0; mi < 2; mi++)
#pragma unroll
                    for (int ni = 0; ni < 8; ni++)
                        acc[mi * 8 + ni] = __builtin_amdgcn_mfma_f32_16x16x32_bf16(
                            aF[mi], bF[ni], acc[mi * 8 + ni], 0, 0, 0);
            }
        }
    }
}

// ---------------------------------------------------------------------------
// Merged Q+KV projection (unchanged from r9-passing).
// ---------------------------------------------------------------------------
__global__ __launch_bounds__(256, 4)
void k_gemm_qkv9(const u16* __restrict__ xall,
                 const u16* __restrict__ wqp, const u16* __restrict__ wkvp,
                 const float* __restrict__ bq, const float* __restrict__ bkv,
                 u16* __restrict__ qb, u16* __restrict__ kb, u16* __restrict__ vt)
{
    __shared__ __align__(16) u16 As[128 * 64];
    __shared__ __align__(16) u16 Bs[128 * 64];

    const int wgid = xcd_swz(blockIdx.x, 134 * 12);
    const int tn = wgid % 12, tm = wgid / 12;
    const int typ = tn >> 2, sub = tn & 3;    // 0=Q, 1=K, 2=V
    const u16* Ab = (typ == 0 ? xall + (size_t)256 * K_ : xall)
                    + (size_t)tm * 128 * K_;
    const u16* Wb = (typ == 0 ? wqp : wkvp + (typ == 2 ? (size_t)512 * K_ : 0))
                    + (size_t)sub * 128 * K_;

    const int tid = threadIdx.x;
    const int w = tid >> 6, lane = tid & 63;
    const int col = lane & 15, quad = lane >> 4;

    f32x4 acc[16];
    if (typ == 2) {
        core128<false>(Ab, Wb, As, Bs, acc);
        const int lq = tm * 2 + (w >> 1);
        const int so = (w & 1) * 2;
#pragma unroll
        for (int ni = 0; ni < 8; ni++) {
            const int f = sub * 128 + ni * 16 + col;
            const float bs = bkv[512 + f];
#pragma unroll
            for (int r = 0; r < 4; r++) {
                const int bb = quad * 4 + r;
                unsigned int pk = cvt_pk_bf16(acc[0 * 8 + ni][r] + bs,
                                              acc[1 * 8 + ni][r] + bs);
                *(unsigned int*)&vt[(((size_t)bb * LQ_ + lq) * 512 + f) * 4 + so] = pk;
            }
        }
    } else {
        core128<true>(Ab, Wb, As, Bs, acc);
        const float* bias = (typ == 0) ? bq : bkv;
        u16* outp = (typ == 0) ? qb : kb;
        const float qs = (typ == 0) ? QSCALE : 1.0f;
#pragma unroll
        for (int ni = 0; ni < 8; ni++) {
            const int gc0 = sub * 128 + ni * 16 + quad * 4;
            const float4 bs4 = *(const float4*)&bias[gc0];
#pragma unroll
            for (int mi = 0; mi < 2; mi++) {
                const int mrow = tm * 128 + w * 32 + mi * 16 + col;
                f32x4 a = acc[ni * 2 + mi];
                uint2 pk;
                pk.x = cvt_pk_bf16((a[0] + bs4.x) * qs, (a[1] + bs4.y) * qs);
                pk.y = cvt_pk_bf16((a[2] + bs4.z) * qs, (a[3] + bs4.w) * qs);
                *(uint2*)&outp[(size_t)mrow * 512 + gc0] = pk;
            }
        }
    }
}

// ---------------------------------------------------------------------------
// Output projection + clip/slice epilogue (unchanged from r9-passing).
// ---------------------------------------------------------------------------
__global__ __launch_bounds__(256, 4)
void k_gemm_o9(const u16* __restrict__ A, const u16* __restrict__ W,
               const float* __restrict__ bias, float* __restrict__ Co)
{
    __shared__ __align__(16) u16 As[128 * 64];
    __shared__ __align__(16) u16 Bs[128 * 64];

    const int wgid = xcd_swz(blockIdx.x, 134 * 4);
    const int tn = wgid % 4, tm = wgid / 4;
    const u16* Ab = A + (size_t)tm * 128 * K_;
    const u16* Wb = W + (size_t)tn * 128 * K_;

    const int tid = threadIdx.x;
    const int w = tid >> 6, lane = tid & 63;
    const int col = lane & 15, quad = lane >> 4;

    f32x4 acc[16];
    core128<true>(Ab, Wb, As, Bs, acc);

#pragma unroll
    for (int ni = 0; ni < 8; ni++) {
        const int gc0 = tn * 128 + ni * 16 + quad * 4;
        const float4 bs4 = *(const float4*)&bias[gc0];
#pragma unroll
        for (int mi = 0; mi < 2; mi++) {
            const int l = tm * 8 + w * 2 + mi;
            if (l == TQ_ - 1) continue;
            const int mrow = tm * 128 + w * 32 + mi * 16 + col;
            f32x4 a = acc[ni * 2 + mi];
            float4 v = {a[0] + bs4.x, a[1] + bs4.y, a[2] + bs4.z, a[3] + bs4.w};
            if (l >= TQ_ - S_) {
                v.x = fminf(10.0f, fmaxf(-10.0f, v.x));
                v.y = fminf(10.0f, fmaxf(-10.0f, v.y));
                v.z = fminf(10.0f, fmaxf(-10.0f, v.z));
                v.w = fminf(10.0f, fmaxf(-10.0f, v.w));
            }
            *(float4*)&Co[(size_t)mrow * 512 + gc0] = v;
        }
    }
}

// ---------------------------------------------------------------------------
// Flash attention v8: TWO q-blocks per workgroup (qhi=16-2p, qlo=qhi-1).
// K-frags and V-frags depend only on the key index -> shared between the
// two q-subs: LDS reads unchanged, global staging HALVED, MFMA+exp2 work
// per staged tile DOUBLED -> stall/compute ratio halves (latency-bound fix).
// Lo-sub skipped via uniform guards where out of causal range.
// ---------------------------------------------------------------------------
__global__ __launch_bounds__(256, 4)
void k_attn5(const u16* __restrict__ qbuf, const u16* __restrict__ kb,
             const u16* __restrict__ vt, const int* __restrict__ lenp,
             u16* __restrict__ attnb)
{
    __shared__ __align__(16) u16 Ks[2][64 * 64];
    __shared__ __align__(16) u16 Vs[2][64 * 64];

    const int blk = blockIdx.x;
    const int pp  = blk >> 7;               // 0..8, heavy pair first
    const int qhi = 16 - 2 * pp;
    const int qlo = qhi - 1;                // -1 for pp=8
    const int bh  = blk & 127;              // blk%8 == h -> head pinned to XCD
    const int b = bh >> 3, h = bh & 7;
    const int tid = threadIdx.x;
    const int w = tid >> 6, lane = tid & 63;
    const int col = lane & 15, quad = lane >> 4;

    int stride = (lenp[1] == 0) ? 2 : 1;
    int maxlen = 0;
    for (int i = 0; i < B_; i++) maxlen = max(maxlen, lenp[i * stride]);
    const int klen = lenp[b * stride] + M_ + (TQ_ - maxlen - S_);

    const int qwh = qhi * 64 + w * 16, qh = qwh + col;
    const int qwl = qlo * 64 + w * 16, ql = qwl + col;
    const bool hasLo = (qlo >= 0);

    const u16* qph = qbuf + ((size_t)min(qh, TQ_ - 1) * B_ + b) * D_ + h * DH_ + quad * 8;
    bf16x8 bqh0 = *(const bf16x8*)(qph);
    bf16x8 bqh1 = *(const bf16x8*)(qph + 32);
    const u16* qpl = qbuf + ((size_t)min(max(ql, 0), TQ_ - 1) * B_ + b) * D_ + h * DH_ + quad * 8;
    bf16x8 bql0 = *(const bf16x8*)(qpl);
    bf16x8 bql1 = *(const bf16x8*)(qpl + 32);

    const int s0 = tid, s1 = tid + 256;
    const u16* kbase = kb + (size_t)b * 512 + h * DH_;
    size_t kof0 = (size_t)(s0 >> 3) * 8192 + (size_t)(((s0 & 7) ^ ((s0 >> 3) & 7)) * 8);
    size_t kof1 = (size_t)(s1 >> 3) * 8192 + (size_t)(((s1 & 7) ^ ((s1 >> 3) & 7)) * 8);
    const u16* vbase = vt + ((size_t)b * LQ_ * 512 + (size_t)h * DH_) * 4;
    auto vchunk = [](int s) -> size_t {
        int fp = s >> 4;
        int lq = (s & 15) ^ (fp & 15);
        return (size_t)lq * 2048 + (size_t)fp * 8;
    };
    const size_t vof0 = vchunk(s0), vof1 = vchunk(s1);

    float lih = 0.f, lil = 0.f;
    f32x4 oh[4], ol[4];
#pragma unroll
    for (int g = 0; g < 4; g++) {
        oh[g] = (f32x4){0.f, 0.f, 0.f, 0.f};
        ol[g] = (f32x4){0.f, 0.f, 0.f, 0.f};
    }

    const int nk_hi = min(qhi * 64 + 64 + M_, klen);
    const int nk_lo = hasLo ? min(qlo * 64 + 64 + M_, klen) : 0;
    const int numkt = (nk_hi + 63) >> 6;

    gload_lds16(kbase + kof0, &Ks[0][(size_t)w * 512]);
    gload_lds16(kbase + kof1, &Ks[0][2048 + (size_t)w * 512]);
    gload_lds16(vbase + vof0, &Vs[0][(size_t)w * 512]);
    gload_lds16(vbase + vof1, &Vs[0][2048 + (size_t)w * 512]);

    for (int kt = 0; kt < numkt; kt++) {
        const int kn0 = kt * 64;
        const int cur = kt & 1;
        const bool loNow = hasLo && (kn0 < nk_lo);
        __syncthreads();
        if (kt + 1 < numkt) {
            const size_t kstep = (size_t)(kn0 + 64) * 8192;
            const size_t vstep = (size_t)(kt + 1) * 32768;
            gload_lds16(kbase + kstep + kof0, &Ks[cur ^ 1][(size_t)w * 512]);
            gload_lds16(kbase + kstep + kof1, &Ks[cur ^ 1][2048 + (size_t)w * 512]);
            gload_lds16(vbase + vstep + vof0, &Vs[cur ^ 1][(size_t)w * 512]);
            gload_lds16(vbase + vstep + vof1, &Vs[cur ^ 1][2048 + (size_t)w * 512]);
        }

        // QK^T for both q-subs; K-frags a0/a1 shared.
        f32x4 sch[4], scl[4];
        __builtin_amdgcn_s_setprio(1);
#pragma unroll
        for (int g = 0; g < 4; g++) {
            int key = g * 16 + col;
            bf16x8 a0 = *(const bf16x8*)&Ks[cur][key * 64 + ((quad ^ (key & 7)) * 8)];
            bf16x8 a1 = *(const bf16x8*)&Ks[cur][key * 64 + (((4 + quad) ^ (key & 7)) * 8)];
            f32x4 z = {0.f, 0.f, 0.f, 0.f};
            z = __builtin_amdgcn_mfma_f32_16x16x32_bf16(a0, bqh0, z, 0, 0, 0);
            z = __builtin_amdgcn_mfma_f32_16x16x32_bf16(a1, bqh1, z, 0, 0, 0);
            sch[g] = z;
            if (loNow) {
                f32x4 y = {0.f, 0.f, 0.f, 0.f};
                y = __builtin_amdgcn_mfma_f32_16x16x32_bf16(a0, bql0, y, 0, 0, 0);
                y = __builtin_amdgcn_mfma_f32_16x16x32_bf16(a1, bql1, y, 0, 0, 0);
                scl[g] = y;
            }
        }
        __builtin_amdgcn_s_setprio(0);

        // boundary-only masking, per sub
        if ((kn0 + 63 > qwh + M_) || (kn0 + 63 >= klen)) {
#pragma unroll
            for (int g = 0; g < 4; g++)
#pragma unroll
                for (int r = 0; r < 4; r++) {
                    int key = kn0 + g * 16 + quad * 4 + r;
                    bool valid = (key <= qh + M_) && (key < klen);
                    sch[g][r] = valid ? sch[g][r] : -1e8f;
                }
        }
        if (loNow && ((kn0 + 63 > qwl + M_) || (kn0 + 63 >= klen))) {
#pragma unroll
            for (int g = 0; g < 4; g++)
#pragma unroll
                for (int r = 0; r < 4; r++) {
                    int key = kn0 + g * 16 + quad * 4 + r;
                    bool valid = (key <= ql + M_) && (key < klen);
                    scl[g][r] = valid ? scl[g][r] : -1e8f;
                }
        }

        // p = exp2(s) -> in-register bf16x4 fragments per sub
        bf16x4 pkh[4], pkl[4];
#pragma unroll
        for (int g = 0; g < 4; g++) {
            float pr[4];
#pragma unroll
            for (int r = 0; r < 4; r++)
                pr[r] = __builtin_amdgcn_exp2f(sch[g][r]);
            lih += (pr[0] + pr[1]) + (pr[2] + pr[3]);
            uint2 pku;
            pku.x = cvt_pk_bf16(pr[0], pr[1]);
            pku.y = cvt_pk_bf16(pr[2], pr[3]);
            pkh[g] = __builtin_bit_cast(bf16x4, pku);
        }
        if (loNow) {
#pragma unroll
            for (int g = 0; g < 4; g++) {
                float pr[4];
#pragma unroll
                for (int r = 0; r < 4; r++)
                    pr[r] = __builtin_amdgcn_exp2f(scl[g][r]);
                lil += (pr[0] + pr[1]) + (pr[2] + pr[3]);
                uint2 pku;
                pku.x = cvt_pk_bf16(pr[0], pr[1]);
                pku.y = cvt_pk_bf16(pr[2], pr[3]);
                pkl[g] = __builtin_bit_cast(bf16x4, pku);
            }
        }

        // PV: V-frag av shared between subs.
        __builtin_amdgcn_s_setprio(1);
#pragma unroll
        for (int g = 0; g < 4; g++) {
            const int d  = g * 16 + col;
            const int fp = d >> 1, fo = (d & 1) * 4;
#pragma unroll
            for (int ks = 0; ks < 4; ks++) {
                const int lq  = ks * 4 + quad;
                const int pos = fp * 16 + (lq ^ (fp & 15));
                bf16x4 av = __builtin_bit_cast(bf16x4,
                    *(const u16x4*)&Vs[cur][pos * 8 + fo]);
                oh[g] = mfma16(av, pkh[ks], oh[g]);
                if (loNow) ol[g] = mfma16(av, pkl[ks], ol[g]);
            }
        }
        __builtin_amdgcn_s_setprio(0);
    }

    // l reductions; q = col lane-local
    lih += __shfl_xor(lih, 16);
    lih += __shfl_xor(lih, 32);
    const float invh = 1.0f / lih;
    if (qwh + 16 <= TQ_) {
#pragma unroll
        for (int g = 0; g < 4; g++) {
            uint2 pkk;
            pkk.x = cvt_pk_bf16(oh[g][0] * invh, oh[g][1] * invh);
            pkk.y = cvt_pk_bf16(oh[g][2] * invh, oh[g][3] * invh);
            *(uint2*)&attnb[((size_t)(qwh + col) * B_ + b) * D_ + h * DH_ + g * 16 + quad * 4] = pkk;
        }
    }
    if (hasLo) {
        lil += __shfl_xor(lil, 16);
        lil += __shfl_xor(lil, 32);
        const float invl = 1.0f / lil;
        if (qwl + 16 <= TQ_) {
#pragma unroll
            for (int g = 0; g < 4; g++) {
                uint2 pkk;
                pkk.x = cvt_pk_bf16(ol[g][0] * invl, ol[g][1] * invl);
                pkk.y = cvt_pk_bf16(ol[g][2] * invl, ol[g][3] * invl);
                *(uint2*)&attnb[((size_t)(qwl + col) * B_ + b) * D_ + h * DH_ + g * 16 + quad * 4] = pkk;
            }
        }
    }
}

// ---------------------------------------------------------------------------
extern "C" void kernel_launch(void* const* d_in, const int* in_sizes, int n_in,
                              void* d_out, int out_size, void* d_ws, size_t ws_size,
                              hipStream_t stream)
{
    const float* utt  = (const float*)d_in[0];
    const int*   len  = (const int*)  d_in[1];
    const float* rc   = (const float*)d_in[2];
    const float* smr  = (const float*)d_in[3];
    const float* mems = (const float*)d_in[4];
    const float* Wq   = (const float*)d_in[6];
    const float* bq   = (const float*)d_in[7];
    const float* Wkv  = (const float*)d_in[8];
    const float* bkv  = (const float*)d_in[9];
    const float* Wo   = (const float*)d_in[10];
    const float* bo   = (const float*)d_in[11];

    char* ws = (char*)d_ws;
    size_t off = 0;
    auto alloc = [&](size_t bytes) -> void* {
        void* p = ws + off;
        off += (bytes + 255) & ~(size_t)255;
        return p;
    };
    u16* xall = (u16*)alloc((size_t)17408 * D_ * 2);
    u16* wq   = (u16*)alloc((size_t)D_ * D_ * 2);
    u16* wkv  = (u16*)alloc((size_t)2 * D_ * D_ * 2);
    u16* wo   = (u16*)alloc((size_t)D_ * D_ * 2);
    u16* qb   = (u16*)alloc((size_t)NROW * D_ * 2);
    u16* kb   = (u16*)alloc((size_t)NROW * D_ * 2);
    u16* vt   = (u16*)alloc((size_t)B_ * LQ_ * 512 * 4 * 2 + 65536);
    u16* attnb = xall;  // xall dead after QKV-GEMM

    k_convert4<<<2048, 256, 0, stream>>>((const float4*)utt, (const float4*)rc,
                                         (const float4*)smr, (const float4*)mems,
                                         (const float4*)Wq, (const float4*)Wkv,
                                         (const float4*)Wo,
                                         (u16x4*)xall,
                                         (u16x4*)wq, (u16x4*)wkv, (u16x4*)wo);
    k_gemm_qkv9<<<134 * 12, 256, 0, stream>>>(xall, wq, wkv, bq, bkv, qb, kb, vt);
    k_attn5<<<9 * 128, 256, 0, stream>>>(qb, kb, vt, len, attnb);
    k_gemm_o9<<<134 * 4, 256, 0, stream>>>(attnb, wo, bo, (float*)d_out);
}

// Round 11
// 213.740 us; speedup vs baseline: 1.0796x; 1.0796x over previous
//
#include <hip/hip_runtime.h>

// Problem constants (Emformer layer)
#define T_   1024
#define B_   16
#define D_   512
#define H_   8
#define R_   32
#define S_   16
#define M_   16
#define TQ_  1072          // R + T + S
#define KL_  1072          // M + R + T
#define DH_  64            // D/H
#define NROW 17152         // TQ*B == KL*B
#define K_   512           // inner dim for ALL three GEMMs
#define LQ_  268           // KL/4 (key-quad groups)
#define QSCALE 0.18033688f // 0.125 * log2(e): folded into Q projection

typedef unsigned short u16;
using bf16x8 = __attribute__((ext_vector_type(8))) short;
using bf16x4 = __attribute__((ext_vector_type(4))) short;
using f32x4  = __attribute__((ext_vector_type(4))) float;
using u16x4  = __attribute__((ext_vector_type(4))) unsigned short;

__device__ __forceinline__ u16 f2bf(float f) {
    unsigned int u = __builtin_bit_cast(unsigned int, f);
    unsigned int r = u + 0x7fffu + ((u >> 16) & 1u);
    return (u16)(r >> 16);
}

// pack 2 f32 -> 2 bf16 in one u32 (RTNE), T12 recipe
__device__ __forceinline__ unsigned int cvt_pk_bf16(float a, float b) {
    unsigned int r;
    asm("v_cvt_pk_bf16_f32 %0, %1, %2" : "=v"(r) : "v"(a), "v"(b));
    return r;
}

// 16x16x16 bf16 MFMA (A,B = 4 bf16 each): PV consumes the QK output's
// natural 4-keys-per-lane granularity -- P stays in registers.
__device__ __forceinline__ f32x4 mfma16(bf16x4 a, bf16x4 b, f32x4 c) {
    asm("v_mfma_f32_16x16x16_bf16 %0, %1, %2, %0" : "+v"(c) : "v"(a), "v"(b));
    return c;
}

// async global->LDS, 16B per lane; LDS dest = wave-uniform base + lane*16
__device__ __forceinline__ void gload_lds16(const u16* g, u16* l) {
    __builtin_amdgcn_global_load_lds(
        (const __attribute__((address_space(1))) unsigned int*)g,
        (__attribute__((address_space(3))) unsigned int*)l,
        16, 0, 0);
}

// bijective XCD swizzle (m204)
__device__ __forceinline__ int xcd_swz(int bid, int nwg) {
    const int q = nwg >> 3, r = nwg & 7;
    const int xcd = bid & 7, idx = bid >> 3;
    return (xcd < r ? xcd * (q + 1) : r * (q + 1) + (xcd - r) * q) + idx;
}

// ---------------------------------------------------------------------------
// Stage 1: single gathered buffer xall = [mems | rc | utt | smr] (17408 rows)
// ---------------------------------------------------------------------------
__global__ void k_convert4(const float4* __restrict__ utt, const float4* __restrict__ rc,
                           const float4* __restrict__ smr, const float4* __restrict__ mems,
                           const float4* __restrict__ Wq, const float4* __restrict__ Wkv,
                           const float4* __restrict__ Wo,
                           u16x4* __restrict__ xall,
                           u16x4* __restrict__ wq, u16x4* __restrict__ wkv,
                           u16x4* __restrict__ wo)
{
    const int N4 = 17408 * D_ / 4;
    const int MB = M_ * B_ * D_ / 4;
    const int RB = MB + R_ * B_ * D_ / 4;
    const int UB = RB + T_ * B_ * D_ / 4;
    const int W1 = D_ * D_ / 4, W2 = 2 * D_ * D_ / 4;
    for (int i = blockIdx.x * blockDim.x + threadIdx.x; i < N4;
         i += gridDim.x * blockDim.x) {
        float4 v;
        if (i < MB)      v = mems[i];
        else if (i < RB) v = rc[i - MB];
        else if (i < UB) v = utt[i - RB];
        else             v = smr[i - UB];
        xall[i] = (u16x4){f2bf(v.x), f2bf(v.y), f2bf(v.z), f2bf(v.w)};
        if (i < W1) {   // Wq and Wo share the i<W1 range: one branch
            v = Wq[i];  wq[i]  = (u16x4){f2bf(v.x), f2bf(v.y), f2bf(v.z), f2bf(v.w)};
            v = Wo[i];  wo[i]  = (u16x4){f2bf(v.x), f2bf(v.y), f2bf(v.z), f2bf(v.w)};
        }
        if (i < W2) { v = Wkv[i]; wkv[i] = (u16x4){f2bf(v.x), f2bf(v.y), f2bf(v.z), f2bf(v.w)}; }
    }
}

// ---------------------------------------------------------------------------
// m97-structure GEMM core: 256 thr / 4 waves, 128x128 tile, BK=64, single
// 32 KB LDS buffer (passed in, shared by both instantiations), 5 blocks/CU.
// ---------------------------------------------------------------------------
template<bool TOR>
__device__ __forceinline__ void core128(const u16* __restrict__ Ab,
                                        const u16* __restrict__ Wb,
                                        u16* As, u16* Bs, f32x4* acc)
{
    const int tid  = threadIdx.x;
    const int w    = tid >> 6, lane = tid & 63;
    const int col  = lane & 15, quad = lane >> 4;
    const int sr   = tid >> 3;                 // 0..31 staging row in round
    const int sc   = (tid & 7) ^ (sr & 7);     // pre-swizzled source chunk
    const u16* gA  = Ab + (size_t)sr * K_ + sc * 8;
    const u16* gB  = Wb + (size_t)sr * K_ + sc * 8;

#pragma unroll
    for (int i = 0; i < 16; i++) acc[i] = (f32x4){0.f, 0.f, 0.f, 0.f};

    for (int kt = 0; kt < 8; ++kt) {
        __syncthreads();
#pragma unroll
        for (int i = 0; i < 4; i++)
            gload_lds16(gA + (size_t)(i * 32) * K_ + kt * 64,
                        &As[(i * 32 + w * 8) * 64]);
#pragma unroll
        for (int i = 0; i < 4; i++)
            gload_lds16(gB + (size_t)(i * 32) * K_ + kt * 64,
                        &Bs[(i * 32 + w * 8) * 64]);
        __syncthreads();
#pragma unroll
        for (int kh = 0; kh < 2; ++kh) {
            bf16x8 aF[2], bF[8];
#pragma unroll
            for (int mi = 0; mi < 2; mi++)
                aF[mi] = *(const bf16x8*)&As[(w * 32 + mi * 16 + col) * 64
                             + (((kh * 4 + quad) ^ (col & 7)) * 8)];
#pragma unroll
            for (int ni = 0; ni < 8; ni++)
                bF[ni] = *(const bf16x8*)&Bs[(ni * 16 + col) * 64
                             + (((kh * 4 + quad) ^ (col & 7)) * 8)];
            if (TOR) {
#pragma unroll
                for (int ni = 0; ni < 8; ni++)
#pragma unroll
                    for (int mi = 0; mi < 2; mi++)
                        acc[ni * 2 + mi] = __builtin_amdgcn_mfma_f32_16x16x32_bf16(
                            bF[ni], aF[mi], acc[ni * 2 + mi], 0, 0, 0);
            } else {
#pragma unroll
                for (int mi = 0; mi < 2; mi++)
#pragma unroll
                    for (int ni = 0; ni < 8; ni++)
                        acc[mi * 8 + ni] = __builtin_amdgcn_mfma_f32_16x16x32_bf16(
                            aF[mi], bF[ni], acc[mi * 8 + ni], 0, 0, 0);
            }
        }
    }
}

// ---------------------------------------------------------------------------
// Merged Q+KV projection (r9-verified).
// ---------------------------------------------------------------------------
__global__ __launch_bounds__(256, 4)
void k_gemm_qkv9(const u16* __restrict__ xall,
                 const u16* __restrict__ wqp, const u16* __restrict__ wkvp,
                 const float* __restrict__ bq, const float* __restrict__ bkv,
                 u16* __restrict__ qb, u16* __restrict__ kb, u16* __restrict__ vt)
{
    __shared__ __align__(16) u16 As[128 * 64];
    __shared__ __align__(16) u16 Bs[128 * 64];

    const int wgid = xcd_swz(blockIdx.x, 134 * 12);
    const int tn = wgid % 12, tm = wgid / 12;
    const int typ = tn >> 2, sub = tn & 3;    // 0=Q, 1=K, 2=V
    const u16* Ab = (typ == 0 ? xall + (size_t)256 * K_ : xall)
                    + (size_t)tm * 128 * K_;
    const u16* Wb = (typ == 0 ? wqp : wkvp + (typ == 2 ? (size_t)512 * K_ : 0))
                    + (size_t)sub * 128 * K_;

    const int tid = threadIdx.x;
    const int w = tid >> 6, lane = tid & 63;
    const int col = lane & 15, quad = lane >> 4;

    f32x4 acc[16];
    if (typ == 2) {
        core128<false>(Ab, Wb, As, Bs, acc);
        const int lq = tm * 2 + (w >> 1);
        const int so = (w & 1) * 2;
#pragma unroll
        for (int ni = 0; ni < 8; ni++) {
            const int f = sub * 128 + ni * 16 + col;
            const float bs = bkv[512 + f];
#pragma unroll
            for (int r = 0; r < 4; r++) {
                const int bb = quad * 4 + r;
                unsigned int pk = cvt_pk_bf16(acc[0 * 8 + ni][r] + bs,
                                              acc[1 * 8 + ni][r] + bs);
                *(unsigned int*)&vt[(((size_t)bb * LQ_ + lq) * 512 + f) * 4 + so] = pk;
            }
        }
    } else {
        core128<true>(Ab, Wb, As, Bs, acc);
        const float* bias = (typ == 0) ? bq : bkv;
        u16* outp = (typ == 0) ? qb : kb;
        const float qs = (typ == 0) ? QSCALE : 1.0f;
#pragma unroll
        for (int ni = 0; ni < 8; ni++) {
            const int gc0 = sub * 128 + ni * 16 + quad * 4;
            const float4 bs4 = *(const float4*)&bias[gc0];
#pragma unroll
            for (int mi = 0; mi < 2; mi++) {
                const int mrow = tm * 128 + w * 32 + mi * 16 + col;
                f32x4 a = acc[ni * 2 + mi];
                uint2 pk;
                pk.x = cvt_pk_bf16((a[0] + bs4.x) * qs, (a[1] + bs4.y) * qs);
                pk.y = cvt_pk_bf16((a[2] + bs4.z) * qs, (a[3] + bs4.w) * qs);
                *(uint2*)&outp[(size_t)mrow * 512 + gc0] = pk;
            }
        }
    }
}

// ---------------------------------------------------------------------------
// Output projection + clip/slice epilogue (r9-verified).
// ---------------------------------------------------------------------------
__global__ __launch_bounds__(256, 4)
void k_gemm_o9(const u16* __restrict__ A, const u16* __restrict__ W,
               const float* __restrict__ bias, float* __restrict__ Co)
{
    __shared__ __align__(16) u16 As[128 * 64];
    __shared__ __align__(16) u16 Bs[128 * 64];

    const int wgid = xcd_swz(blockIdx.x, 134 * 4);
    const int tn = wgid % 4, tm = wgid / 4;
    const u16* Ab = A + (size_t)tm * 128 * K_;
    const u16* Wb = W + (size_t)tn * 128 * K_;

    const int tid = threadIdx.x;
    const int w = tid >> 6, lane = tid & 63;
    const int col = lane & 15, quad = lane >> 4;

    f32x4 acc[16];
    core128<true>(Ab, Wb, As, Bs, acc);

#pragma unroll
    for (int ni = 0; ni < 8; ni++) {
        const int gc0 = tn * 128 + ni * 16 + quad * 4;
        const float4 bs4 = *(const float4*)&bias[gc0];
#pragma unroll
        for (int mi = 0; mi < 2; mi++) {
            const int l = tm * 8 + w * 2 + mi;
            if (l == TQ_ - 1) continue;
            const int mrow = tm * 128 + w * 32 + mi * 16 + col;
            f32x4 a = acc[ni * 2 + mi];
            float4 v = {a[0] + bs4.x, a[1] + bs4.y, a[2] + bs4.z, a[3] + bs4.w};
            if (l >= TQ_ - S_) {
                v.x = fminf(10.0f, fmaxf(-10.0f, v.x));
                v.y = fminf(10.0f, fmaxf(-10.0f, v.y));
                v.z = fminf(10.0f, fmaxf(-10.0f, v.z));
                v.w = fminf(10.0f, fmaxf(-10.0f, v.w));
            }
            *(float4*)&Co[(size_t)mrow * 512 + gc0] = v;
        }
    }
}

// ---------------------------------------------------------------------------
// Flash attention v7 (r9-verified, 200.1 µs config): PV via 16x16x16 MFMA,
// P in registers, no Ps LDS, 32 KB LDS, one q-block per workgroup (heavy
// first). r10's q-pairing REVERTED: pairing heavy qblks doubled the
// critical path (makespan 17->33 tile-units) and regressed 47->69 µs.
// ---------------------------------------------------------------------------
__global__ __launch_bounds__(256, 4)
void k_attn5(const u16* __restrict__ qbuf, const u16* __restrict__ kb,
             const u16* __restrict__ vt, const int* __restrict__ lenp,
             u16* __restrict__ attnb)
{
    __shared__ __align__(16) u16 Ks[2][64 * 64];
    __shared__ __align__(16) u16 Vs[2][64 * 64];

    const int blk  = blockIdx.x;
    const int qblk = 16 - (blk >> 7);       // heavy (qblk=16) first
    const int bh   = blk & 127;             // blk%8 == h -> head pinned to XCD
    const int b = bh >> 3, h = bh & 7;
    const int tid = threadIdx.x;
    const int w = tid >> 6, lane = tid & 63;
    const int col = lane & 15, quad = lane >> 4;

    int stride = (lenp[1] == 0) ? 2 : 1;
    int maxlen = 0;
    for (int i = 0; i < B_; i++) maxlen = max(maxlen, lenp[i * stride]);
    const int klen = lenp[b * stride] + M_ + (TQ_ - maxlen - S_);

    const int q0 = qblk * 64;
    const int qw = q0 + w * 16;
    const int q  = qw + col;

    int qrow = min(q, TQ_ - 1);
    const u16* qp = qbuf + ((size_t)qrow * B_ + b) * D_ + h * DH_ + quad * 8;
    bf16x8 bq0 = *(const bf16x8*)(qp);
    bf16x8 bq1 = *(const bf16x8*)(qp + 32);

    const int s0 = tid, s1 = tid + 256;
    const u16* kbase = kb + (size_t)b * 512 + h * DH_;
    size_t kof0 = (size_t)(s0 >> 3) * 8192 + (size_t)(((s0 & 7) ^ ((s0 >> 3) & 7)) * 8);
    size_t kof1 = (size_t)(s1 >> 3) * 8192 + (size_t)(((s1 & 7) ^ ((s1 >> 3) & 7)) * 8);
    const u16* vbase = vt + ((size_t)b * LQ_ * 512 + (size_t)h * DH_) * 4;
    auto vchunk = [](int s) -> size_t {
        int fp = s >> 4;
        int lq = (s & 15) ^ (fp & 15);
        return (size_t)lq * 2048 + (size_t)fp * 8;
    };
    const size_t vof0 = vchunk(s0), vof1 = vchunk(s1);

    float li = 0.f;                         // per-lane partial sum of p (q = col)
    f32x4 o[4];
#pragma unroll
    for (int g = 0; g < 4; g++) o[g] = (f32x4){0.f, 0.f, 0.f, 0.f};

    const int nk = min(q0 + 64 + M_, klen);
    const int numkt = (nk + 63) >> 6;

    gload_lds16(kbase + kof0, &Ks[0][(size_t)w * 512]);
    gload_lds16(kbase + kof1, &Ks[0][2048 + (size_t)w * 512]);
    gload_lds16(vbase + vof0, &Vs[0][(size_t)w * 512]);
    gload_lds16(vbase + vof1, &Vs[0][2048 + (size_t)w * 512]);

    for (int kt = 0; kt < numkt; kt++) {
        const int kn0 = kt * 64;
        const int cur = kt & 1;
        __syncthreads();
        if (kt + 1 < numkt) {
            const size_t kstep = (size_t)(kn0 + 64) * 8192;
            const size_t vstep = (size_t)(kt + 1) * 32768;
            gload_lds16(kbase + kstep + kof0, &Ks[cur ^ 1][(size_t)w * 512]);
            gload_lds16(kbase + kstep + kof1, &Ks[cur ^ 1][2048 + (size_t)w * 512]);
            gload_lds16(vbase + vstep + vof0, &Vs[cur ^ 1][(size_t)w * 512]);
            gload_lds16(vbase + vstep + vof1, &Vs[cur ^ 1][2048 + (size_t)w * 512]);
        }

        // QK^T (Q pre-scaled into exp2 domain): sc[g][r] = S[kn0+g*16+quad*4+r][q=col]
        f32x4 sc[4];
        __builtin_amdgcn_s_setprio(1);
#pragma unroll
        for (int g = 0; g < 4; g++) {
            int key = g * 16 + col;
            bf16x8 a0 = *(const bf16x8*)&Ks[cur][key * 64 + ((quad ^ (key & 7)) * 8)];
            bf16x8 a1 = *(const bf16x8*)&Ks[cur][key * 64 + (((4 + quad) ^ (key & 7)) * 8)];
            f32x4 z = {0.f, 0.f, 0.f, 0.f};
            z = __builtin_amdgcn_mfma_f32_16x16x32_bf16(a0, bq0, z, 0, 0, 0);
            z = __builtin_amdgcn_mfma_f32_16x16x32_bf16(a1, bq1, z, 0, 0, 0);
            sc[g] = z;
        }
        __builtin_amdgcn_s_setprio(0);

        // boundary-only masking
        const bool needmask = (kn0 + 63 > qw + M_) || (kn0 + 63 >= klen);
        if (needmask) {
#pragma unroll
            for (int g = 0; g < 4; g++)
#pragma unroll
                for (int r = 0; r < 4; r++) {
                    int key = kn0 + g * 16 + quad * 4 + r;
                    bool valid = (key <= q + M_) && (key < klen);
                    sc[g][r] = valid ? sc[g][r] : -1e8f;
                }
        }

        // p = exp2(s): in-register bf16x4 fragments
        bf16x4 pk[4];
#pragma unroll
        for (int g = 0; g < 4; g++) {
            float pr[4];
#pragma unroll
            for (int r = 0; r < 4; r++)
                pr[r] = __builtin_amdgcn_exp2f(sc[g][r]);
            li += (pr[0] + pr[1]) + (pr[2] + pr[3]);
            uint2 pku;
            pku.x = cvt_pk_bf16(pr[0], pr[1]);
            pku.y = cvt_pk_bf16(pr[2], pr[3]);
            pk[g] = __builtin_bit_cast(bf16x4, pku);
        }

        // PV: o[g] += sum_ks mfma16(V-frag, pk[ks]); D[d=g*16+quad*4+r][q=col]
        __builtin_amdgcn_s_setprio(1);
#pragma unroll
        for (int g = 0; g < 4; g++) {
            const int d  = g * 16 + col;
            const int fp = d >> 1, fo = (d & 1) * 4;
#pragma unroll
            for (int ks = 0; ks < 4; ks++) {
                const int lq  = ks * 4 + quad;
                const int pos = fp * 16 + (lq ^ (fp & 15));
                bf16x4 av = __builtin_bit_cast(bf16x4,
                    *(const u16x4*)&Vs[cur][pos * 8 + fo]);
                o[g] = mfma16(av, pk[ks], o[g]);
            }
        }
        __builtin_amdgcn_s_setprio(0);
    }

    // l reduction across quads; q = col is lane-local so inv applies directly
    li += __shfl_xor(li, 16);
    li += __shfl_xor(li, 32);
    const float inv = 1.0f / li;
    const int qo = qw + col;
    if (qw + 16 <= TQ_) {
#pragma unroll
        for (int g = 0; g < 4; g++) {
            uint2 pkk;
            pkk.x = cvt_pk_bf16(o[g][0] * inv, o[g][1] * inv);
            pkk.y = cvt_pk_bf16(o[g][2] * inv, o[g][3] * inv);
            *(uint2*)&attnb[((size_t)qo * B_ + b) * D_ + h * DH_ + g * 16 + quad * 4] = pkk;
        }
    }
}

// ---------------------------------------------------------------------------
extern "C" void kernel_launch(void* const* d_in, const int* in_sizes, int n_in,
                              void* d_out, int out_size, void* d_ws, size_t ws_size,
                              hipStream_t stream)
{
    const float* utt  = (const float*)d_in[0];
    const int*   len  = (const int*)  d_in[1];
    const float* rc   = (const float*)d_in[2];
    const float* smr  = (const float*)d_in[3];
    const float* mems = (const float*)d_in[4];
    const float* Wq   = (const float*)d_in[6];
    const float* bq   = (const float*)d_in[7];
    const float* Wkv  = (const float*)d_in[8];
    const float* bkv  = (const float*)d_in[9];
    const float* Wo   = (const float*)d_in[10];
    const float* bo   = (const float*)d_in[11];

    char* ws = (char*)d_ws;
    size_t off = 0;
    auto alloc = [&](size_t bytes) -> void* {
        void* p = ws + off;
        off += (bytes + 255) & ~(size_t)255;
        return p;
    };
    u16* xall = (u16*)alloc((size_t)17408 * D_ * 2);
    u16* wq   = (u16*)alloc((size_t)D_ * D_ * 2);
    u16* wkv  = (u16*)alloc((size_t)2 * D_ * D_ * 2);
    u16* wo   = (u16*)alloc((size_t)D_ * D_ * 2);
    u16* qb   = (u16*)alloc((size_t)NROW * D_ * 2);
    u16* kb   = (u16*)alloc((size_t)NROW * D_ * 2);
    u16* vt   = (u16*)alloc((size_t)B_ * LQ_ * 512 * 4 * 2 + 65536);
    u16* attnb = xall;  // xall dead after QKV-GEMM

    k_convert4<<<2048, 256, 0, stream>>>((const float4*)utt, (const float4*)rc,
                                         (const float4*)smr, (const float4*)mems,
                                         (const float4*)Wq, (const float4*)Wkv,
                                         (const float4*)Wo,
                                         (u16x4*)xall,
                                         (u16x4*)wq, (u16x4*)wkv, (u16x4*)wo);
    k_gemm_qkv9<<<134 * 12, 256, 0, stream>>>(xall, wq, wkv, bq, bkv, qb, kb, vt);
    k_attn5<<<17 * 128, 256, 0, stream>>>(qb, kb, vt, len, attnb);
    k_gemm_o9<<<134 * 4, 256, 0, stream>>>(attnb, wo, bo, (float*)d_out);
}